// Round 1
// baseline (2495.120 us; speedup 1.0000x reference)
//
#include <hip/hip_runtime.h>

#define N_NODES 100000
#define NNZ_E   3200000
#define SLOPE   0.25f

// ---------------- CSR build ----------------
__global__ __launch_bounds__(256) void hist_kernel(const int* __restrict__ rows,
                                                   int* __restrict__ counts) {
    int e = blockIdx.x * blockDim.x + threadIdx.x;
    if (e < NNZ_E) atomicAdd(&counts[rows[e]], 1);
}

__global__ __launch_bounds__(1024) void scan_kernel(const int* __restrict__ counts,
                                                    int* __restrict__ row_off,
                                                    int* __restrict__ cursor) {
    const int t = threadIdx.x;
    const int CHUNK = (N_NODES + 1023) / 1024;  // 98
    int base = t * CHUNK;
    int lim = base + CHUNK; if (lim > N_NODES) lim = N_NODES;
    if (base > N_NODES) base = N_NODES;
    int sum = 0;
    for (int i = base; i < lim; ++i) sum += counts[i];
    __shared__ int lds[1024];
    lds[t] = sum;
    __syncthreads();
    for (int off = 1; off < 1024; off <<= 1) {
        int v = (t >= off) ? lds[t - off] : 0;
        __syncthreads();
        lds[t] += v;
        __syncthreads();
    }
    int run = lds[t] - sum;  // exclusive prefix for this thread's chunk
    for (int i = base; i < lim; ++i) {
        row_off[i] = run;
        cursor[i]  = run;
        run += counts[i];
    }
    if (t == 0) row_off[N_NODES] = NNZ_E;
}

__global__ __launch_bounds__(256) void scatter_kernel(const int* __restrict__ rows,
                                                      const int* __restrict__ cols,
                                                      const float* __restrict__ vals,
                                                      int* __restrict__ cursor,
                                                      int* __restrict__ ecol,
                                                      float* __restrict__ eval) {
    int e = blockIdx.x * blockDim.x + threadIdx.x;
    if (e < NNZ_E) {
        int pos = atomicAdd(&cursor[rows[e]], 1);
        ecol[pos] = cols[e];
        eval[pos] = vals[e];
    }
}

// ---------------- fp32 tiled GEMM: C[M,Nc] = A[M,K] @ W[K,Nc] ----------------
// 64x64 tile, 256 threads, 4x4 microtile, BK=16.
__global__ __launch_bounds__(256) void gemm_kernel(const float* __restrict__ A,
                                                   const float* __restrict__ W,
                                                   float* __restrict__ C,
                                                   int M, int K, int Nc) {
    __shared__ float As[16][68];  // padded to break conflicts; 272B row = 16B aligned
    __shared__ float Bs[16][68];
    const int t  = threadIdx.x;
    const int tx = t & 15, ty = t >> 4;
    const int row0 = blockIdx.y * 64;
    const int col0 = blockIdx.x * 64;

    float acc[4][4] = {};

    const int arow = t >> 2;          // 0..63
    const int acol = (t & 3) << 2;    // 0,4,8,12
    const int brow = t >> 4;          // 0..15
    const int bcol = (t & 15) << 2;   // 0..60

    for (int k0 = 0; k0 < K; k0 += 16) {
        float4 a4 = make_float4(0.f, 0.f, 0.f, 0.f);
        int ar = row0 + arow;
        if (ar < M) a4 = *(const float4*)&A[(size_t)ar * K + k0 + acol];
        As[acol + 0][arow] = a4.x;
        As[acol + 1][arow] = a4.y;
        As[acol + 2][arow] = a4.z;
        As[acol + 3][arow] = a4.w;
        float4 b4 = *(const float4*)&W[(size_t)(k0 + brow) * Nc + col0 + bcol];
        *(float4*)&Bs[brow][bcol] = b4;
        __syncthreads();
#pragma unroll
        for (int kk = 0; kk < 16; ++kk) {
            float4 av = *(const float4*)&As[kk][ty << 2];
            float4 bv = *(const float4*)&Bs[kk][tx << 2];
            float aa[4] = {av.x, av.y, av.z, av.w};
            float bb[4] = {bv.x, bv.y, bv.z, bv.w};
#pragma unroll
            for (int i = 0; i < 4; ++i)
#pragma unroll
                for (int j = 0; j < 4; ++j) acc[i][j] += aa[i] * bb[j];
        }
        __syncthreads();
    }
#pragma unroll
    for (int i = 0; i < 4; ++i) {
        int r = row0 + (ty << 2) + i;
        if (r < M) {
            float4 o = make_float4(acc[i][0], acc[i][1], acc[i][2], acc[i][3]);
            *(float4*)&C[(size_t)r * Nc + col0 + (tx << 2)] = o;
        }
    }
}

// ---------------- CSR SpMM, one wave per row ----------------
// D = 256: lane owns 4 contiguous floats (float4 gather, 1KB/edge coalesced)
__global__ __launch_bounds__(256) void spmm256_kernel(const int* __restrict__ row_off,
                                                      const int* __restrict__ ecol,
                                                      const float* __restrict__ eval,
                                                      const float* __restrict__ support,
                                                      const float* __restrict__ bias,
                                                      float* __restrict__ out) {
    int wave = (blockIdx.x << 2) + (threadIdx.x >> 6);
    if (wave >= N_NODES) return;
    int lane = threadIdx.x & 63;
    int s = row_off[wave], e = row_off[wave + 1];
    int cb = lane << 2;  // column base
    float4 acc = make_float4(0.f, 0.f, 0.f, 0.f);
    int i = s;
    for (; i + 2 <= e; i += 2) {
        int c0 = ecol[i], c1 = ecol[i + 1];
        float v0 = eval[i], v1 = eval[i + 1];
        float4 x0 = *(const float4*)&support[((size_t)c0 << 8) + cb];
        float4 x1 = *(const float4*)&support[((size_t)c1 << 8) + cb];
        acc.x += v0 * x0.x; acc.y += v0 * x0.y; acc.z += v0 * x0.z; acc.w += v0 * x0.w;
        acc.x += v1 * x1.x; acc.y += v1 * x1.y; acc.z += v1 * x1.z; acc.w += v1 * x1.w;
    }
    if (i < e) {
        int c0 = ecol[i]; float v0 = eval[i];
        float4 x0 = *(const float4*)&support[((size_t)c0 << 8) + cb];
        acc.x += v0 * x0.x; acc.y += v0 * x0.y; acc.z += v0 * x0.z; acc.w += v0 * x0.w;
    }
    float4 bv = *(const float4*)&bias[cb];
    float o0 = acc.x + bv.x, o1 = acc.y + bv.y, o2 = acc.z + bv.z, o3 = acc.w + bv.w;
    o0 = (o0 >= 0.f) ? o0 : SLOPE * o0;
    o1 = (o1 >= 0.f) ? o1 : SLOPE * o1;
    o2 = (o2 >= 0.f) ? o2 : SLOPE * o2;
    o3 = (o3 >= 0.f) ? o3 : SLOPE * o3;
    *(float4*)&out[((size_t)wave << 8) + cb] = make_float4(o0, o1, o2, o3);
}

// D = 128: lane owns 2 contiguous floats
__global__ __launch_bounds__(256) void spmm128_kernel(const int* __restrict__ row_off,
                                                      const int* __restrict__ ecol,
                                                      const float* __restrict__ eval,
                                                      const float* __restrict__ support,
                                                      const float* __restrict__ bias,
                                                      float* __restrict__ out) {
    int wave = (blockIdx.x << 2) + (threadIdx.x >> 6);
    if (wave >= N_NODES) return;
    int lane = threadIdx.x & 63;
    int s = row_off[wave], e = row_off[wave + 1];
    int cb = lane << 1;
    float2 acc = make_float2(0.f, 0.f);
    int i = s;
    for (; i + 2 <= e; i += 2) {
        int c0 = ecol[i], c1 = ecol[i + 1];
        float v0 = eval[i], v1 = eval[i + 1];
        float2 x0 = *(const float2*)&support[((size_t)c0 << 7) + cb];
        float2 x1 = *(const float2*)&support[((size_t)c1 << 7) + cb];
        acc.x += v0 * x0.x; acc.y += v0 * x0.y;
        acc.x += v1 * x1.x; acc.y += v1 * x1.y;
    }
    if (i < e) {
        int c0 = ecol[i]; float v0 = eval[i];
        float2 x0 = *(const float2*)&support[((size_t)c0 << 7) + cb];
        acc.x += v0 * x0.x; acc.y += v0 * x0.y;
    }
    float2 bv = *(const float2*)&bias[cb];
    float o0 = acc.x + bv.x, o1 = acc.y + bv.y;
    o0 = (o0 >= 0.f) ? o0 : SLOPE * o0;
    o1 = (o1 >= 0.f) ? o1 : SLOPE * o1;
    *(float2*)&out[((size_t)wave << 7) + cb] = make_float2(o0, o1);
}

// ---------------- launch ----------------
extern "C" void kernel_launch(void* const* d_in, const int* in_sizes, int n_in,
                              void* d_out, int out_size, void* d_ws, size_t ws_size,
                              hipStream_t stream) {
    const float* x     = (const float*)d_in[0];
    const int*   arows = (const int*)d_in[1];
    const int*   acols = (const int*)d_in[2];
    const float* avals = (const float*)d_in[3];
    const float* W1 = (const float*)d_in[4];
    const float* b1 = (const float*)d_in[5];
    const float* W2 = (const float*)d_in[6];
    const float* b2 = (const float*)d_in[7];
    const float* W3 = (const float*)d_in[8];
    const float* b3 = (const float*)d_in[9];
    float* out = (float*)d_out;

    // workspace carve (all 16B-aligned)
    char* ws = (char*)d_ws;
    float* bufA = (float*)(ws);                       // N*256 f32 = 102,400,000 B
    float* bufB = (float*)(ws + 102400000);           // N*256 f32
    float* eval = (float*)(ws + 204800000);           // NNZ f32 = 12,800,000 B
    int*   ecol = (int*)  (ws + 217600000);           // NNZ i32
    int*   roff = (int*)  (ws + 230400000);           // N+1 i32 (padded slot 400,128 B)
    int*   curs = (int*)  (ws + 230800128);           // N i32
    int*   cnts = (int*)  (ws + 231200128);           // N i32

    // CSR build (per call; ws is re-poisoned each timed launch)
    hipMemsetAsync(cnts, 0, N_NODES * sizeof(int), stream);
    hist_kernel<<<NNZ_E / 256, 256, 0, stream>>>(arows, cnts);
    scan_kernel<<<1, 1024, 0, stream>>>(cnts, roff, curs);
    scatter_kernel<<<NNZ_E / 256, 256, 0, stream>>>(arows, acols, avals, curs, ecol, eval);

    const int gy = (N_NODES + 63) / 64;  // 1563

    // layer 1: support = x @ W1 [100000,256]; h1 = leaky(spmm + b1)
    gemm_kernel<<<dim3(4, gy), 256, 0, stream>>>(x, W1, bufA, N_NODES, 512, 256);
    spmm256_kernel<<<25000, 256, 0, stream>>>(roff, ecol, eval, bufA, b1, bufB);
    // layer 2
    gemm_kernel<<<dim3(4, gy), 256, 0, stream>>>(bufB, W2, bufA, N_NODES, 256, 256);
    spmm256_kernel<<<25000, 256, 0, stream>>>(roff, ecol, eval, bufA, b2, bufB);
    // layer 3 (out dim 128)
    gemm_kernel<<<dim3(2, gy), 256, 0, stream>>>(bufB, W3, bufA, N_NODES, 256, 128);
    spmm128_kernel<<<25000, 256, 0, stream>>>(roff, ecol, eval, bufA, b3, out);
}

// Round 2
// 1646.441 us; speedup vs baseline: 1.5155x; 1.5155x over previous
//
#include <hip/hip_runtime.h>

#define N_NODES 100000
#define NNZ_E   3200000
#define SLOPE   0.25f

typedef __attribute__((ext_vector_type(8))) short bf16x8;
typedef __attribute__((ext_vector_type(4))) float f32x4;

// f32 -> bf16 round-to-nearest-even (bit trick)
__device__ __forceinline__ unsigned short f2b(float f) {
    union { float f; unsigned int u; } c; c.f = f;
    unsigned int u = c.u + 0x7fffu + ((c.u >> 16) & 1u);
    return (unsigned short)(u >> 16);
}
// packed uint -> two f32 (low half, high half)
__device__ __forceinline__ float b2f_lo(unsigned int u) {
    union { unsigned int u; float f; } c; c.u = u << 16; return c.f;
}
__device__ __forceinline__ float b2f_hi(unsigned int u) {
    union { unsigned int u; float f; } c; c.u = u & 0xffff0000u; return c.f;
}

// ---------------- CSR build ----------------
__global__ __launch_bounds__(256) void hist_kernel(const int* __restrict__ rows,
                                                   int* __restrict__ counts) {
    int e = blockIdx.x * blockDim.x + threadIdx.x;
    if (e < NNZ_E) atomicAdd(&counts[rows[e]], 1);
}

__global__ __launch_bounds__(1024) void scan_kernel(const int* __restrict__ counts,
                                                    int* __restrict__ row_off,
                                                    int* __restrict__ cursor) {
    const int t = threadIdx.x;
    const int CHUNK = (N_NODES + 1023) / 1024;  // 98
    int base = t * CHUNK;
    int lim = base + CHUNK; if (lim > N_NODES) lim = N_NODES;
    if (base > N_NODES) base = N_NODES;
    int sum = 0;
    for (int i = base; i < lim; ++i) sum += counts[i];
    __shared__ int lds[1024];
    lds[t] = sum;
    __syncthreads();
    for (int off = 1; off < 1024; off <<= 1) {
        int v = (t >= off) ? lds[t - off] : 0;
        __syncthreads();
        lds[t] += v;
        __syncthreads();
    }
    int run = lds[t] - sum;
    for (int i = base; i < lim; ++i) {
        row_off[i] = run;
        cursor[i]  = run;
        run += counts[i];
    }
    if (t == 0) row_off[N_NODES] = NNZ_E;
}

__global__ __launch_bounds__(256) void scatter_kernel(const int* __restrict__ rows,
                                                      const int* __restrict__ cols,
                                                      const float* __restrict__ vals,
                                                      int* __restrict__ cursor,
                                                      int* __restrict__ ecol,
                                                      float* __restrict__ eval) {
    int e = blockIdx.x * blockDim.x + threadIdx.x;
    if (e < NNZ_E) {
        int pos = atomicAdd(&cursor[rows[e]], 1);
        ecol[pos] = cols[e];
        eval[pos] = vals[e];
    }
}

// ---------------- dtype prep ----------------
// f32 -> bf16, 4 elems/thread (n divisible by 4)
__global__ __launch_bounds__(256) void conv_kernel(const float* __restrict__ in,
                                                   unsigned short* __restrict__ out,
                                                   int n4) {
    int i = blockIdx.x * blockDim.x + threadIdx.x;
    if (i < n4) {
        float4 v = *(const float4*)&in[i << 2];
        ushort4 o;
        o.x = f2b(v.x); o.y = f2b(v.y); o.z = f2b(v.z); o.w = f2b(v.w);
        *(ushort4*)&out[i << 2] = o;
    }
}

// W[K,N] f32 -> Wt[N,K] bf16 (tiny)
__global__ __launch_bounds__(256) void wprep_kernel(const float* __restrict__ W,
                                                    unsigned short* __restrict__ Wt,
                                                    int K, int Nc) {
    int idx = blockIdx.x * blockDim.x + threadIdx.x;
    if (idx < K * Nc) {
        int n = idx / K, k = idx - n * K;
        Wt[idx] = f2b(W[(size_t)k * Nc + n]);
    }
}

// ---------------- bf16 MFMA GEMM: C[M,Nc] = A[M,K] @ Bt[Nc,K]^T ----------------
// 64x64 block tile, BK=32, 256 threads (4 waves, 2x2 wave grid, 32x32 per wave)
__global__ __launch_bounds__(256) void gemm_bf16_kernel(
    const unsigned short* __restrict__ A,   // [M,K] bf16
    const unsigned short* __restrict__ Bt,  // [Nc,K] bf16
    unsigned short* __restrict__ C,         // [M,Nc] bf16
    int M, int K, int Nc)
{
    __shared__ __align__(16) unsigned short As[64 * 32];
    __shared__ __align__(16) unsigned short Bs[64 * 32];
    const int t = threadIdx.x;
    const int wave = t >> 6, lane = t & 63;
    const int wm = wave & 1, wn = wave >> 1;
    const int quad = lane >> 4, l16 = lane & 15;
    const int row0 = blockIdx.y * 64, col0 = blockIdx.x * 64;

    f32x4 acc[2][2];
#pragma unroll
    for (int mt = 0; mt < 2; ++mt)
#pragma unroll
        for (int nt = 0; nt < 2; ++nt) acc[mt][nt] = (f32x4){0.f, 0.f, 0.f, 0.f};

    const int lr = t >> 2;         // 0..63
    const int lk = (t & 3) << 3;   // 0,8,16,24

    for (int k0 = 0; k0 < K; k0 += 32) {
        uint4 av = make_uint4(0, 0, 0, 0);
        int ar = row0 + lr;
        if (ar < M) av = *(const uint4*)&A[(size_t)ar * K + k0 + lk];
        *(uint4*)&As[lr * 32 + lk] = av;
        uint4 bv = *(const uint4*)&Bt[(size_t)(col0 + lr) * K + k0 + lk];
        *(uint4*)&Bs[lr * 32 + lk] = bv;
        __syncthreads();
        bf16x8 afr[2], bfr[2];
#pragma unroll
        for (int mt = 0; mt < 2; ++mt)
            afr[mt] = *(const bf16x8*)&As[(wm * 32 + mt * 16 + l16) * 32 + quad * 8];
#pragma unroll
        for (int nt = 0; nt < 2; ++nt)
            bfr[nt] = *(const bf16x8*)&Bs[(wn * 32 + nt * 16 + l16) * 32 + quad * 8];
#pragma unroll
        for (int mt = 0; mt < 2; ++mt)
#pragma unroll
            for (int nt = 0; nt < 2; ++nt)
                acc[mt][nt] = __builtin_amdgcn_mfma_f32_16x16x32_bf16(
                    afr[mt], bfr[nt], acc[mt][nt], 0, 0, 0);
        __syncthreads();
    }
    // C/D layout: col = lane&15, row = quad*4 + r
#pragma unroll
    for (int mt = 0; mt < 2; ++mt)
#pragma unroll
        for (int r = 0; r < 4; ++r) {
            int row = row0 + wm * 32 + mt * 16 + quad * 4 + r;
            if (row < M) {
#pragma unroll
                for (int nt = 0; nt < 2; ++nt) {
                    int col = col0 + wn * 32 + nt * 16 + l16;
                    C[(size_t)row * Nc + col] = f2b(acc[mt][nt][r]);
                }
            }
        }
}

// ---------------- CSR SpMM, bf16 support gather, one wave per row ----------------
// D=256: lane owns 4 bf16 cols (8B gather/lane -> 512B/edge/wave), bf16 out
__global__ __launch_bounds__(256) void spmm256b_kernel(const int* __restrict__ row_off,
                                                       const int* __restrict__ ecol,
                                                       const float* __restrict__ eval,
                                                       const unsigned short* __restrict__ sup,
                                                       const float* __restrict__ bias,
                                                       unsigned short* __restrict__ out) {
    int row = (blockIdx.x << 2) + (threadIdx.x >> 6);
    if (row >= N_NODES) return;
    int lane = threadIdx.x & 63;
    int s = row_off[row], e = row_off[row + 1];
    int cb = lane << 2;
    float a0 = 0.f, a1 = 0.f, a2 = 0.f, a3 = 0.f;
    int i = s;
    for (; i + 2 <= e; i += 2) {
        int c0 = ecol[i], c1 = ecol[i + 1];
        float v0 = eval[i], v1 = eval[i + 1];
        uint2 g0 = *(const uint2*)&sup[((size_t)c0 << 8) + cb];
        uint2 g1 = *(const uint2*)&sup[((size_t)c1 << 8) + cb];
        a0 += v0 * b2f_lo(g0.x); a1 += v0 * b2f_hi(g0.x);
        a2 += v0 * b2f_lo(g0.y); a3 += v0 * b2f_hi(g0.y);
        a0 += v1 * b2f_lo(g1.x); a1 += v1 * b2f_hi(g1.x);
        a2 += v1 * b2f_lo(g1.y); a3 += v1 * b2f_hi(g1.y);
    }
    if (i < e) {
        int c0 = ecol[i]; float v0 = eval[i];
        uint2 g0 = *(const uint2*)&sup[((size_t)c0 << 8) + cb];
        a0 += v0 * b2f_lo(g0.x); a1 += v0 * b2f_hi(g0.x);
        a2 += v0 * b2f_lo(g0.y); a3 += v0 * b2f_hi(g0.y);
    }
    float4 bv = *(const float4*)&bias[cb];
    a0 += bv.x; a1 += bv.y; a2 += bv.z; a3 += bv.w;
    a0 = (a0 >= 0.f) ? a0 : SLOPE * a0;
    a1 = (a1 >= 0.f) ? a1 : SLOPE * a1;
    a2 = (a2 >= 0.f) ? a2 : SLOPE * a2;
    a3 = (a3 >= 0.f) ? a3 : SLOPE * a3;
    ushort4 o; o.x = f2b(a0); o.y = f2b(a1); o.z = f2b(a2); o.w = f2b(a3);
    *(ushort4*)&out[((size_t)row << 8) + cb] = o;
}

// D=128: lane owns 2 bf16 cols, fp32 out (final layer)
__global__ __launch_bounds__(256) void spmm128f_kernel(const int* __restrict__ row_off,
                                                       const int* __restrict__ ecol,
                                                       const float* __restrict__ eval,
                                                       const unsigned short* __restrict__ sup,
                                                       const float* __restrict__ bias,
                                                       float* __restrict__ out) {
    int row = (blockIdx.x << 2) + (threadIdx.x >> 6);
    if (row >= N_NODES) return;
    int lane = threadIdx.x & 63;
    int s = row_off[row], e = row_off[row + 1];
    int cb = lane << 1;
    float a0 = 0.f, a1 = 0.f;
    int i = s;
    for (; i + 2 <= e; i += 2) {
        int c0 = ecol[i], c1 = ecol[i + 1];
        float v0 = eval[i], v1 = eval[i + 1];
        unsigned int g0 = *(const unsigned int*)&sup[((size_t)c0 << 7) + cb];
        unsigned int g1 = *(const unsigned int*)&sup[((size_t)c1 << 7) + cb];
        a0 += v0 * b2f_lo(g0); a1 += v0 * b2f_hi(g0);
        a0 += v1 * b2f_lo(g1); a1 += v1 * b2f_hi(g1);
    }
    if (i < e) {
        int c0 = ecol[i]; float v0 = eval[i];
        unsigned int g0 = *(const unsigned int*)&sup[((size_t)c0 << 7) + cb];
        a0 += v0 * b2f_lo(g0); a1 += v0 * b2f_hi(g0);
    }
    float2 bv = *(const float2*)&bias[cb];
    a0 += bv.x; a1 += bv.y;
    a0 = (a0 >= 0.f) ? a0 : SLOPE * a0;
    a1 = (a1 >= 0.f) ? a1 : SLOPE * a1;
    *(float2*)&out[((size_t)row << 7) + cb] = make_float2(a0, a1);
}

// ---------------- launch ----------------
extern "C" void kernel_launch(void* const* d_in, const int* in_sizes, int n_in,
                              void* d_out, int out_size, void* d_ws, size_t ws_size,
                              hipStream_t stream) {
    const float* x     = (const float*)d_in[0];
    const int*   arows = (const int*)d_in[1];
    const int*   acols = (const int*)d_in[2];
    const float* avals = (const float*)d_in[3];
    const float* W1 = (const float*)d_in[4];
    const float* b1 = (const float*)d_in[5];
    const float* W2 = (const float*)d_in[6];
    const float* b2 = (const float*)d_in[7];
    const float* W3 = (const float*)d_in[8];
    const float* b3 = (const float*)d_in[9];
    float* out = (float*)d_out;

    // workspace carve — max footprint identical to round 1 (231,600,128 B)
    char* ws = (char*)d_ws;
    unsigned short* xb   = (unsigned short*)(ws);                 // 100000*512 bf16 = 102,400,000 B
    unsigned short* bufS = (unsigned short*)(ws + 102400000);     // 100000*256 bf16 = 51,200,000 B
    unsigned short* bufH = (unsigned short*)(ws + 153600000);     // 100000*256 bf16
    float* eval = (float*)(ws + 204800000);                       // NNZ f32
    int*   ecol = (int*)  (ws + 217600000);                       // NNZ i32
    int*   roff = (int*)  (ws + 230400000);                       // N+1 i32
    int*   curs = (int*)  (ws + 230800128);                       // N i32 (free after scatter)
    int*   cnts = (int*)  (ws + 231200128);                       // N i32 (free after scan)
    // overlays (launched after the region's last reader):
    unsigned short* Wt1 = (unsigned short*)(ws + 231200128);      // 512*256 bf16 = 262,144 B over cnts
    unsigned short* Wt2 = (unsigned short*)(ws + 230800128);      // 256*256 bf16 = 131,072 B over curs
    unsigned short* Wt3 = (unsigned short*)(ws + 230800128 + 131072); // 256*128 bf16 = 65,536 B

    // CSR build
    hipMemsetAsync(cnts, 0, N_NODES * sizeof(int), stream);
    hist_kernel<<<NNZ_E / 256, 256, 0, stream>>>(arows, cnts);
    scan_kernel<<<1, 1024, 0, stream>>>(cnts, roff, curs);
    wprep_kernel<<<(512 * 256 + 255) / 256, 256, 0, stream>>>(W1, Wt1, 512, 256); // cnts dead
    scatter_kernel<<<NNZ_E / 256, 256, 0, stream>>>(arows, acols, avals, curs, ecol, eval);
    wprep_kernel<<<(256 * 256 + 255) / 256, 256, 0, stream>>>(W2, Wt2, 256, 256); // curs dead
    wprep_kernel<<<(256 * 128 + 255) / 256, 256, 0, stream>>>(W3, Wt3, 256, 128);

    // x -> bf16
    conv_kernel<<<(100000 * 512 / 4 + 255) / 256, 256, 0, stream>>>(x, xb, 100000 * 512 / 4);

    const int gy = (N_NODES + 63) / 64;  // 1563

    // layer 1
    gemm_bf16_kernel<<<dim3(4, gy), 256, 0, stream>>>(xb, Wt1, bufS, N_NODES, 512, 256);
    spmm256b_kernel<<<25000, 256, 0, stream>>>(roff, ecol, eval, bufS, b1, bufH);
    // layer 2
    gemm_bf16_kernel<<<dim3(4, gy), 256, 0, stream>>>(bufH, Wt2, bufS, N_NODES, 256, 256);
    spmm256b_kernel<<<25000, 256, 0, stream>>>(roff, ecol, eval, bufS, b2, bufH);
    // layer 3
    gemm_bf16_kernel<<<dim3(2, gy), 256, 0, stream>>>(bufH, Wt3, bufS, N_NODES, 256, 128);
    spmm128f_kernel<<<25000, 256, 0, stream>>>(roff, ecol, eval, bufS, b3, out);
}

// Round 3
// 1528.942 us; speedup vs baseline: 1.6319x; 1.0768x over previous
//
#include <hip/hip_runtime.h>

#define N_NODES 100000
#define NNZ_E   3200000
#define SLOPE   0.25f

typedef __attribute__((ext_vector_type(8))) short bf16x8;
typedef __attribute__((ext_vector_type(4))) float f32x4;

// f32 -> bf16 round-to-nearest-even (bit trick)
__device__ __forceinline__ unsigned short f2b(float f) {
    union { float f; unsigned int u; } c; c.f = f;
    unsigned int u = c.u + 0x7fffu + ((c.u >> 16) & 1u);
    return (unsigned short)(u >> 16);
}
__device__ __forceinline__ float b2f_lo(unsigned int u) {
    union { unsigned int u; float f; } c; c.u = u << 16; return c.f;
}
__device__ __forceinline__ float b2f_hi(unsigned int u) {
    union { unsigned int u; float f; } c; c.u = u & 0xffff0000u; return c.f;
}

// async global->LDS, 16B per lane; LDS dest is wave-uniform base + lane*16
__device__ __forceinline__ void load_lds16(const unsigned short* gp, unsigned short* lp) {
    __builtin_amdgcn_global_load_lds(
        (const __attribute__((address_space(1))) void*)gp,
        (__attribute__((address_space(3))) void*)lp, 16, 0, 0);
}

// ---------------- CSR build ----------------
__global__ __launch_bounds__(256) void hist_kernel(const int* __restrict__ rows,
                                                   int* __restrict__ counts) {
    int e = blockIdx.x * blockDim.x + threadIdx.x;
    if (e < NNZ_E) atomicAdd(&counts[rows[e]], 1);
}

__global__ __launch_bounds__(1024) void scan_kernel(const int* __restrict__ counts,
                                                    int* __restrict__ row_off,
                                                    int* __restrict__ cursor) {
    const int t = threadIdx.x;
    const int CHUNK = (N_NODES + 1023) / 1024;  // 98
    int base = t * CHUNK;
    int lim = base + CHUNK; if (lim > N_NODES) lim = N_NODES;
    if (base > N_NODES) base = N_NODES;
    int sum = 0;
    for (int i = base; i < lim; ++i) sum += counts[i];
    __shared__ int lds[1024];
    lds[t] = sum;
    __syncthreads();
    for (int off = 1; off < 1024; off <<= 1) {
        int v = (t >= off) ? lds[t - off] : 0;
        __syncthreads();
        lds[t] += v;
        __syncthreads();
    }
    int run = lds[t] - sum;
    for (int i = base; i < lim; ++i) {
        row_off[i] = run;
        cursor[i]  = run;
        run += counts[i];
    }
    if (t == 0) row_off[N_NODES] = NNZ_E;
}

__global__ __launch_bounds__(256) void scatter_kernel(const int* __restrict__ rows,
                                                      const int* __restrict__ cols,
                                                      const float* __restrict__ vals,
                                                      int* __restrict__ cursor,
                                                      int* __restrict__ ecol,
                                                      float* __restrict__ eval) {
    int e = blockIdx.x * blockDim.x + threadIdx.x;
    if (e < NNZ_E) {
        int pos = atomicAdd(&cursor[rows[e]], 1);
        ecol[pos] = cols[e];
        eval[pos] = vals[e];
    }
}

// ---------------- dtype prep ----------------
__global__ __launch_bounds__(256) void conv_kernel(const float* __restrict__ in,
                                                   unsigned short* __restrict__ out,
                                                   int n4) {
    int i = blockIdx.x * blockDim.x + threadIdx.x;
    if (i < n4) {
        float4 v = *(const float4*)&in[i << 2];
        ushort4 o;
        o.x = f2b(v.x); o.y = f2b(v.y); o.z = f2b(v.z); o.w = f2b(v.w);
        *(ushort4*)&out[i << 2] = o;
    }
}

__global__ __launch_bounds__(256) void wprep_kernel(const float* __restrict__ W,
                                                    unsigned short* __restrict__ Wt,
                                                    int K, int Nc) {
    int idx = blockIdx.x * blockDim.x + threadIdx.x;
    if (idx < K * Nc) {
        int n = idx / K, k = idx - n * K;
        Wt[idx] = f2b(W[(size_t)k * Nc + n]);
    }
}

// ---------------- bf16 MFMA GEMM (m97 structure) ----------------
// C[M,Nc] = A[M,K] @ Bt[Nc,K]^T. 128x128 block tile, BK=32, 256 threads,
// 4 waves 2x2 (64x64/wave = 4x4 MFMA 16x16x32), global_load_lds width-16 staging.
__global__ __launch_bounds__(256) void gemm_bf16_128(
    const unsigned short* __restrict__ A,   // [M,K] bf16
    const unsigned short* __restrict__ Bt,  // [Nc,K] bf16
    unsigned short* __restrict__ C,         // [M,Nc] bf16
    int M, int K, int Nc)
{
    __shared__ __align__(16) unsigned short As[128 * 32];  // 8 KB
    __shared__ __align__(16) unsigned short Bs[128 * 32];  // 8 KB
    const int t = threadIdx.x;
    const int wave = t >> 6, lane = t & 63;
    const int wm = wave & 1, wn = wave >> 1;
    const int quad = lane >> 4, l16 = lane & 15;
    const int row0 = blockIdx.y * 128, col0 = blockIdx.x * 128;

    f32x4 acc[4][4];
#pragma unroll
    for (int mt = 0; mt < 4; ++mt)
#pragma unroll
        for (int nt = 0; nt < 4; ++nt) acc[mt][nt] = (f32x4){0.f, 0.f, 0.f, 0.f};

    // staging: chunk c (c = wave + 4*j, j in {0,1}) covers LDS bytes [c*1024, +1024)
    // = tile rows [c*16, c*16+16), lane l -> row c*16 + (l>>2), col (l&3)*8
    const int sr0 = wave * 16 + (lane >> 2);        // chunk j=0 row-in-tile
    const int sr1 = sr0 + 64;                       // chunk j=1 row-in-tile
    const int sc  = (lane & 3) << 3;                // col in tile (bf16 elems)

    int ra0 = row0 + sr0; if (ra0 > M - 1) ra0 = M - 1;
    int ra1 = row0 + sr1; if (ra1 > M - 1) ra1 = M - 1;
    const int rb0 = col0 + sr0;                     // Nc multiple of 128: no clamp
    const int rb1 = col0 + sr1;

    for (int k0 = 0; k0 < K; k0 += 32) {
        __syncthreads();  // all waves done reading previous tile
        load_lds16(&A [(size_t)ra0 * K + k0 + sc], &As[(size_t)wave * 512]);
        load_lds16(&A [(size_t)ra1 * K + k0 + sc], &As[(size_t)(wave + 4) * 512]);
        load_lds16(&Bt[(size_t)rb0 * K + k0 + sc], &Bs[(size_t)wave * 512]);
        load_lds16(&Bt[(size_t)rb1 * K + k0 + sc], &Bs[(size_t)(wave + 4) * 512]);
        __syncthreads();  // per-wave vmcnt(0) drain before barrier -> staging done

        bf16x8 af[4], bf[4];
#pragma unroll
        for (int mt = 0; mt < 4; ++mt)
            af[mt] = *(const bf16x8*)&As[(wm * 64 + mt * 16 + l16) * 32 + quad * 8];
#pragma unroll
        for (int nt = 0; nt < 4; ++nt)
            bf[nt] = *(const bf16x8*)&Bs[(wn * 64 + nt * 16 + l16) * 32 + quad * 8];
#pragma unroll
        for (int mt = 0; mt < 4; ++mt)
#pragma unroll
            for (int nt = 0; nt < 4; ++nt)
                acc[mt][nt] = __builtin_amdgcn_mfma_f32_16x16x32_bf16(
                    af[mt], bf[nt], acc[mt][nt], 0, 0, 0);
    }

    // C/D layout: col = l16, row = quad*4 + r
#pragma unroll
    for (int mt = 0; mt < 4; ++mt)
#pragma unroll
        for (int r = 0; r < 4; ++r) {
            int row = row0 + wm * 64 + mt * 16 + quad * 4 + r;
            if (row < M) {
#pragma unroll
                for (int nt = 0; nt < 4; ++nt) {
                    int col = col0 + wn * 64 + nt * 16 + l16;
                    C[(size_t)row * Nc + col] = f2b(acc[mt][nt][r]);
                }
            }
        }
}

// ---------------- CSR SpMM, bf16 support gather, one wave per row ----------------
__global__ __launch_bounds__(256) void spmm256b_kernel(const int* __restrict__ row_off,
                                                       const int* __restrict__ ecol,
                                                       const float* __restrict__ eval,
                                                       const unsigned short* __restrict__ sup,
                                                       const float* __restrict__ bias,
                                                       unsigned short* __restrict__ out) {
    int row = (blockIdx.x << 2) + (threadIdx.x >> 6);
    if (row >= N_NODES) return;
    int lane = threadIdx.x & 63;
    int s = row_off[row], e = row_off[row + 1];
    int cb = lane << 2;
    float a0 = 0.f, a1 = 0.f, a2 = 0.f, a3 = 0.f;
    int i = s;
    for (; i + 4 <= e; i += 4) {
        int c0 = ecol[i], c1 = ecol[i + 1], c2 = ecol[i + 2], c3 = ecol[i + 3];
        float v0 = eval[i], v1 = eval[i + 1], v2 = eval[i + 2], v3 = eval[i + 3];
        uint2 g0 = *(const uint2*)&sup[((size_t)c0 << 8) + cb];
        uint2 g1 = *(const uint2*)&sup[((size_t)c1 << 8) + cb];
        uint2 g2 = *(const uint2*)&sup[((size_t)c2 << 8) + cb];
        uint2 g3 = *(const uint2*)&sup[((size_t)c3 << 8) + cb];
        a0 += v0 * b2f_lo(g0.x); a1 += v0 * b2f_hi(g0.x);
        a2 += v0 * b2f_lo(g0.y); a3 += v0 * b2f_hi(g0.y);
        a0 += v1 * b2f_lo(g1.x); a1 += v1 * b2f_hi(g1.x);
        a2 += v1 * b2f_lo(g1.y); a3 += v1 * b2f_hi(g1.y);
        a0 += v2 * b2f_lo(g2.x); a1 += v2 * b2f_hi(g2.x);
        a2 += v2 * b2f_lo(g2.y); a3 += v2 * b2f_hi(g2.y);
        a0 += v3 * b2f_lo(g3.x); a1 += v3 * b2f_hi(g3.x);
        a2 += v3 * b2f_lo(g3.y); a3 += v3 * b2f_hi(g3.y);
    }
    for (; i < e; ++i) {
        int c0 = ecol[i]; float v0 = eval[i];
        uint2 g0 = *(const uint2*)&sup[((size_t)c0 << 8) + cb];
        a0 += v0 * b2f_lo(g0.x); a1 += v0 * b2f_hi(g0.x);
        a2 += v0 * b2f_lo(g0.y); a3 += v0 * b2f_hi(g0.y);
    }
    float4 bv = *(const float4*)&bias[cb];
    a0 += bv.x; a1 += bv.y; a2 += bv.z; a3 += bv.w;
    a0 = (a0 >= 0.f) ? a0 : SLOPE * a0;
    a1 = (a1 >= 0.f) ? a1 : SLOPE * a1;
    a2 = (a2 >= 0.f) ? a2 : SLOPE * a2;
    a3 = (a3 >= 0.f) ? a3 : SLOPE * a3;
    ushort4 o; o.x = f2b(a0); o.y = f2b(a1); o.z = f2b(a2); o.w = f2b(a3);
    *(ushort4*)&out[((size_t)row << 8) + cb] = o;
}

__global__ __launch_bounds__(256) void spmm128f_kernel(const int* __restrict__ row_off,
                                                       const int* __restrict__ ecol,
                                                       const float* __restrict__ eval,
                                                       const unsigned short* __restrict__ sup,
                                                       const float* __restrict__ bias,
                                                       float* __restrict__ out) {
    int row = (blockIdx.x << 2) + (threadIdx.x >> 6);
    if (row >= N_NODES) return;
    int lane = threadIdx.x & 63;
    int s = row_off[row], e = row_off[row + 1];
    int cb = lane << 1;
    float a0 = 0.f, a1 = 0.f;
    int i = s;
    for (; i + 4 <= e; i += 4) {
        int c0 = ecol[i], c1 = ecol[i + 1], c2 = ecol[i + 2], c3 = ecol[i + 3];
        float v0 = eval[i], v1 = eval[i + 1], v2 = eval[i + 2], v3 = eval[i + 3];
        unsigned int g0 = *(const unsigned int*)&sup[((size_t)c0 << 7) + cb];
        unsigned int g1 = *(const unsigned int*)&sup[((size_t)c1 << 7) + cb];
        unsigned int g2 = *(const unsigned int*)&sup[((size_t)c2 << 7) + cb];
        unsigned int g3 = *(const unsigned int*)&sup[((size_t)c3 << 7) + cb];
        a0 += v0 * b2f_lo(g0); a1 += v0 * b2f_hi(g0);
        a0 += v1 * b2f_lo(g1); a1 += v1 * b2f_hi(g1);
        a0 += v2 * b2f_lo(g2); a1 += v2 * b2f_hi(g2);
        a0 += v3 * b2f_lo(g3); a1 += v3 * b2f_hi(g3);
    }
    for (; i < e; ++i) {
        int c0 = ecol[i]; float v0 = eval[i];
        unsigned int g0 = *(const unsigned int*)&sup[((size_t)c0 << 7) + cb];
        a0 += v0 * b2f_lo(g0); a1 += v0 * b2f_hi(g0);
    }
    float2 bv = *(const float2*)&bias[cb];
    a0 += bv.x; a1 += bv.y;
    a0 = (a0 >= 0.f) ? a0 : SLOPE * a0;
    a1 = (a1 >= 0.f) ? a1 : SLOPE * a1;
    *(float2*)&out[((size_t)row << 7) + cb] = make_float2(a0, a1);
}

// ---------------- launch ----------------
extern "C" void kernel_launch(void* const* d_in, const int* in_sizes, int n_in,
                              void* d_out, int out_size, void* d_ws, size_t ws_size,
                              hipStream_t stream) {
    const float* x     = (const float*)d_in[0];
    const int*   arows = (const int*)d_in[1];
    const int*   acols = (const int*)d_in[2];
    const float* avals = (const float*)d_in[3];
    const float* W1 = (const float*)d_in[4];
    const float* b1 = (const float*)d_in[5];
    const float* W2 = (const float*)d_in[6];
    const float* b2 = (const float*)d_in[7];
    const float* W3 = (const float*)d_in[8];
    const float* b3 = (const float*)d_in[9];
    float* out = (float*)d_out;

    char* ws = (char*)d_ws;
    unsigned short* xb   = (unsigned short*)(ws);                 // 100000*512 bf16
    unsigned short* bufS = (unsigned short*)(ws + 102400000);     // 100000*256 bf16
    unsigned short* bufH = (unsigned short*)(ws + 153600000);     // 100000*256 bf16
    float* eval = (float*)(ws + 204800000);                       // NNZ f32
    int*   ecol = (int*)  (ws + 217600000);                       // NNZ i32
    int*   roff = (int*)  (ws + 230400000);                       // N+1 i32
    int*   curs = (int*)  (ws + 230800128);                       // N i32 (free after scatter)
    int*   cnts = (int*)  (ws + 231200128);                       // N i32 (free after scan)
    unsigned short* Wt1 = (unsigned short*)(ws + 231200128);      // over cnts
    unsigned short* Wt2 = (unsigned short*)(ws + 230800128);      // over curs
    unsigned short* Wt3 = (unsigned short*)(ws + 230800128 + 131072);

    // CSR build
    hipMemsetAsync(cnts, 0, N_NODES * sizeof(int), stream);
    hist_kernel<<<NNZ_E / 256, 256, 0, stream>>>(arows, cnts);
    scan_kernel<<<1, 1024, 0, stream>>>(cnts, roff, curs);
    wprep_kernel<<<(512 * 256 + 255) / 256, 256, 0, stream>>>(W1, Wt1, 512, 256); // cnts dead
    scatter_kernel<<<NNZ_E / 256, 256, 0, stream>>>(arows, acols, avals, curs, ecol, eval);
    wprep_kernel<<<(256 * 256 + 255) / 256, 256, 0, stream>>>(W2, Wt2, 256, 256); // curs dead
    wprep_kernel<<<(256 * 128 + 255) / 256, 256, 0, stream>>>(W3, Wt3, 256, 128);

    conv_kernel<<<(100000 * 512 / 4 + 255) / 256, 256, 0, stream>>>(x, xb, 100000 * 512 / 4);

    const int gyc = (N_NODES + 127) / 128;  // 782

    // layer 1
    gemm_bf16_128<<<dim3(2, gyc), 256, 0, stream>>>(xb, Wt1, bufS, N_NODES, 512, 256);
    spmm256b_kernel<<<25000, 256, 0, stream>>>(roff, ecol, eval, bufS, b1, bufH);
    // layer 2
    gemm_bf16_128<<<dim3(2, gyc), 256, 0, stream>>>(bufH, Wt2, bufS, N_NODES, 256, 256);
    spmm256b_kernel<<<25000, 256, 0, stream>>>(roff, ecol, eval, bufS, b2, bufH);
    // layer 3
    gemm_bf16_128<<<dim3(1, gyc), 256, 0, stream>>>(bufH, Wt3, bufS, N_NODES, 256, 128);
    spmm128f_kernel<<<25000, 256, 0, stream>>>(roff, ecol, eval, bufS, b3, out);
}

// Round 4
// 1353.511 us; speedup vs baseline: 1.8434x; 1.1296x over previous
//
#include <hip/hip_runtime.h>

#define N_NODES 100000
#define NNZ_E   3200000
#define SLOPE   0.25f
#define NBLK_SCAN 98   // ceil(100000/1024)

typedef __attribute__((ext_vector_type(8))) short bf16x8;
typedef __attribute__((ext_vector_type(4))) float f32x4;

// f32 -> bf16 round-to-nearest-even (bit trick)
__device__ __forceinline__ unsigned short f2b(float f) {
    union { float f; unsigned int u; } c; c.f = f;
    unsigned int u = c.u + 0x7fffu + ((c.u >> 16) & 1u);
    return (unsigned short)(u >> 16);
}
__device__ __forceinline__ float b2f_lo(unsigned int u) {
    union { unsigned int u; float f; } c; c.u = u << 16; return c.f;
}
__device__ __forceinline__ float b2f_hi(unsigned int u) {
    union { unsigned int u; float f; } c; c.u = u & 0xffff0000u; return c.f;
}

// async global->LDS, 16B per lane; LDS dest is wave-uniform base + lane*16
__device__ __forceinline__ void load_lds16(const unsigned short* gp, unsigned short* lp) {
    __builtin_amdgcn_global_load_lds(
        (const __attribute__((address_space(1))) void*)gp,
        (__attribute__((address_space(3))) void*)lp, 16, 0, 0);
}

// ---------------- CSR build ----------------
__global__ __launch_bounds__(256) void hist_kernel(const int* __restrict__ rows,
                                                   int* __restrict__ counts) {
    int e = blockIdx.x * blockDim.x + threadIdx.x;
    if (e < NNZ_E) atomicAdd(&counts[rows[e]], 1);
}

// phase 1: per-1024-elem chunk sums (256 thr x int4)
__global__ __launch_bounds__(256) void chunk_sum_kernel(const int* __restrict__ counts,
                                                        int* __restrict__ bsum) {
    int b = blockIdx.x, t = threadIdx.x;
    int base = b * 1024 + t * 4;
    int s = 0;
    if (base < N_NODES) {  // N_NODES % 4 == 0: int4 group all-in or all-out
        int4 v = *(const int4*)&counts[base];
        s = v.x + v.y + v.z + v.w;
    }
    __shared__ int red[256];
    red[t] = s; __syncthreads();
    for (int off = 128; off > 0; off >>= 1) {
        if (t < off) red[t] += red[t + off];
        __syncthreads();
    }
    if (t == 0) bsum[b] = red[0];
}

// phase 2: exclusive scan of the 98 chunk sums (one tiny block)
__global__ __launch_bounds__(128) void bsum_scan_kernel(const int* __restrict__ bsum,
                                                        int* __restrict__ boff) {
    int t = threadIdx.x;
    __shared__ int lds[128];
    int v = (t < NBLK_SCAN) ? bsum[t] : 0;
    lds[t] = v; __syncthreads();
    for (int off = 1; off < 128; off <<= 1) {
        int u = (t >= off) ? lds[t - off] : 0;
        __syncthreads();
        lds[t] += u;
        __syncthreads();
    }
    if (t < NBLK_SCAN) boff[t] = lds[t] - v;  // exclusive
}

// phase 3: local scan + chunk offset, write row_off & cursor
__global__ __launch_bounds__(256) void scan_apply_kernel(const int* __restrict__ counts,
                                                         const int* __restrict__ boff,
                                                         int* __restrict__ row_off,
                                                         int* __restrict__ cursor) {
    int b = blockIdx.x, t = threadIdx.x;
    int base = b * 1024 + t * 4;
    int4 v = make_int4(0, 0, 0, 0);
    if (base < N_NODES) v = *(const int4*)&counts[base];
    int s = v.x + v.y + v.z + v.w;
    __shared__ int lds[256];
    lds[t] = s; __syncthreads();
    for (int off = 1; off < 256; off <<= 1) {
        int u = (t >= off) ? lds[t - off] : 0;
        __syncthreads();
        lds[t] += u;
        __syncthreads();
    }
    int run = boff[b] + lds[t] - s;  // exclusive prefix for this thread's 4 elems
    if (base < N_NODES) {
        row_off[base + 0] = run; cursor[base + 0] = run; run += v.x;
        row_off[base + 1] = run; cursor[base + 1] = run; run += v.y;
        row_off[base + 2] = run; cursor[base + 2] = run; run += v.z;
        row_off[base + 3] = run; cursor[base + 3] = run; run += v.w;
    }
    if (b == 0 && t == 0) row_off[N_NODES] = NNZ_E;
}

__global__ __launch_bounds__(256) void scatter_kernel(const int* __restrict__ rows,
                                                      const int* __restrict__ cols,
                                                      const float* __restrict__ vals,
                                                      int* __restrict__ cursor,
                                                      int2* __restrict__ epack) {
    int e = blockIdx.x * blockDim.x + threadIdx.x;
    if (e < NNZ_E) {
        int pos = atomicAdd(&cursor[rows[e]], 1);
        epack[pos] = make_int2(cols[e], __float_as_int(vals[e]));
    }
}

// ---------------- dtype prep ----------------
__global__ __launch_bounds__(256) void conv_kernel(const float* __restrict__ in,
                                                   unsigned short* __restrict__ out,
                                                   int n4) {
    int i = blockIdx.x * blockDim.x + threadIdx.x;
    if (i < n4) {
        float4 v = *(const float4*)&in[i << 2];
        ushort4 o;
        o.x = f2b(v.x); o.y = f2b(v.y); o.z = f2b(v.z); o.w = f2b(v.w);
        *(ushort4*)&out[i << 2] = o;
    }
}

__global__ __launch_bounds__(256) void wprep_kernel(const float* __restrict__ W,
                                                    unsigned short* __restrict__ Wt,
                                                    int K, int Nc) {
    int idx = blockIdx.x * blockDim.x + threadIdx.x;
    if (idx < K * Nc) {
        int n = idx / K, k = idx - n * K;
        Wt[idx] = f2b(W[(size_t)k * Nc + n]);
    }
}

// ---------------- bf16 MFMA GEMM (m97 structure) ----------------
__global__ __launch_bounds__(256) void gemm_bf16_128(
    const unsigned short* __restrict__ A,   // [M,K] bf16
    const unsigned short* __restrict__ Bt,  // [Nc,K] bf16
    unsigned short* __restrict__ C,         // [M,Nc] bf16
    int M, int K, int Nc)
{
    __shared__ __align__(16) unsigned short As[128 * 32];
    __shared__ __align__(16) unsigned short Bs[128 * 32];
    const int t = threadIdx.x;
    const int wave = t >> 6, lane = t & 63;
    const int wm = wave & 1, wn = wave >> 1;
    const int quad = lane >> 4, l16 = lane & 15;
    const int row0 = blockIdx.y * 128, col0 = blockIdx.x * 128;

    f32x4 acc[4][4];
#pragma unroll
    for (int mt = 0; mt < 4; ++mt)
#pragma unroll
        for (int nt = 0; nt < 4; ++nt) acc[mt][nt] = (f32x4){0.f, 0.f, 0.f, 0.f};

    const int sr0 = wave * 16 + (lane >> 2);
    const int sr1 = sr0 + 64;
    const int sc  = (lane & 3) << 3;

    int ra0 = row0 + sr0; if (ra0 > M - 1) ra0 = M - 1;
    int ra1 = row0 + sr1; if (ra1 > M - 1) ra1 = M - 1;
    const int rb0 = col0 + sr0;
    const int rb1 = col0 + sr1;

    for (int k0 = 0; k0 < K; k0 += 32) {
        __syncthreads();
        load_lds16(&A [(size_t)ra0 * K + k0 + sc], &As[(size_t)wave * 512]);
        load_lds16(&A [(size_t)ra1 * K + k0 + sc], &As[(size_t)(wave + 4) * 512]);
        load_lds16(&Bt[(size_t)rb0 * K + k0 + sc], &Bs[(size_t)wave * 512]);
        load_lds16(&Bt[(size_t)rb1 * K + k0 + sc], &Bs[(size_t)(wave + 4) * 512]);
        __syncthreads();

        bf16x8 af[4], bf[4];
#pragma unroll
        for (int mt = 0; mt < 4; ++mt)
            af[mt] = *(const bf16x8*)&As[(wm * 64 + mt * 16 + l16) * 32 + quad * 8];
#pragma unroll
        for (int nt = 0; nt < 4; ++nt)
            bf[nt] = *(const bf16x8*)&Bs[(wn * 64 + nt * 16 + l16) * 32 + quad * 8];
#pragma unroll
        for (int mt = 0; mt < 4; ++mt)
#pragma unroll
            for (int nt = 0; nt < 4; ++nt)
                acc[mt][nt] = __builtin_amdgcn_mfma_f32_16x16x32_bf16(
                    af[mt], bf[nt], acc[mt][nt], 0, 0, 0);
    }

#pragma unroll
    for (int mt = 0; mt < 4; ++mt)
#pragma unroll
        for (int r = 0; r < 4; ++r) {
            int row = row0 + wm * 64 + mt * 16 + quad * 4 + r;
            if (row < M) {
#pragma unroll
                for (int nt = 0; nt < 4; ++nt) {
                    int col = col0 + wn * 64 + nt * 16 + l16;
                    C[(size_t)row * Nc + col] = f2b(acc[mt][nt][r]);
                }
            }
        }
}

// ---------------- CSR SpMM, bf16 support gather, one wave per row ----------------
__global__ __launch_bounds__(256) void spmm256b_kernel(const int* __restrict__ row_off,
                                                       const int2* __restrict__ ep,
                                                       const unsigned short* __restrict__ sup,
                                                       const float* __restrict__ bias,
                                                       unsigned short* __restrict__ out) {
    int row = (blockIdx.x << 2) + (threadIdx.x >> 6);
    if (row >= N_NODES) return;
    int lane = threadIdx.x & 63;
    int s = row_off[row], e = row_off[row + 1];
    int cb = lane << 2;
    float a0 = 0.f, a1 = 0.f, a2 = 0.f, a3 = 0.f;
    int i = s;
    for (; i + 4 <= e; i += 4) {
        int2 p0 = ep[i], p1 = ep[i + 1], p2 = ep[i + 2], p3 = ep[i + 3];
        float v0 = __int_as_float(p0.y), v1 = __int_as_float(p1.y);
        float v2 = __int_as_float(p2.y), v3 = __int_as_float(p3.y);
        uint2 g0 = *(const uint2*)&sup[((size_t)p0.x << 8) + cb];
        uint2 g1 = *(const uint2*)&sup[((size_t)p1.x << 8) + cb];
        uint2 g2 = *(const uint2*)&sup[((size_t)p2.x << 8) + cb];
        uint2 g3 = *(const uint2*)&sup[((size_t)p3.x << 8) + cb];
        a0 += v0 * b2f_lo(g0.x); a1 += v0 * b2f_hi(g0.x);
        a2 += v0 * b2f_lo(g0.y); a3 += v0 * b2f_hi(g0.y);
        a0 += v1 * b2f_lo(g1.x); a1 += v1 * b2f_hi(g1.x);
        a2 += v1 * b2f_lo(g1.y); a3 += v1 * b2f_hi(g1.y);
        a0 += v2 * b2f_lo(g2.x); a1 += v2 * b2f_hi(g2.x);
        a2 += v2 * b2f_lo(g2.y); a3 += v2 * b2f_hi(g2.y);
        a0 += v3 * b2f_lo(g3.x); a1 += v3 * b2f_hi(g3.x);
        a2 += v3 * b2f_lo(g3.y); a3 += v3 * b2f_hi(g3.y);
    }
    for (; i < e; ++i) {
        int2 p0 = ep[i];
        float v0 = __int_as_float(p0.y);
        uint2 g0 = *(const uint2*)&sup[((size_t)p0.x << 8) + cb];
        a0 += v0 * b2f_lo(g0.x); a1 += v0 * b2f_hi(g0.x);
        a2 += v0 * b2f_lo(g0.y); a3 += v0 * b2f_hi(g0.y);
    }
    float4 bv = *(const float4*)&bias[cb];
    a0 += bv.x; a1 += bv.y; a2 += bv.z; a3 += bv.w;
    a0 = (a0 >= 0.f) ? a0 : SLOPE * a0;
    a1 = (a1 >= 0.f) ? a1 : SLOPE * a1;
    a2 = (a2 >= 0.f) ? a2 : SLOPE * a2;
    a3 = (a3 >= 0.f) ? a3 : SLOPE * a3;
    ushort4 o; o.x = f2b(a0); o.y = f2b(a1); o.z = f2b(a2); o.w = f2b(a3);
    *(ushort4*)&out[((size_t)row << 8) + cb] = o;
}

__global__ __launch_bounds__(256) void spmm128f_kernel(const int* __restrict__ row_off,
                                                       const int2* __restrict__ ep,
                                                       const unsigned short* __restrict__ sup,
                                                       const float* __restrict__ bias,
                                                       float* __restrict__ out) {
    int row = (blockIdx.x << 2) + (threadIdx.x >> 6);
    if (row >= N_NODES) return;
    int lane = threadIdx.x & 63;
    int s = row_off[row], e = row_off[row + 1];
    int cb = lane << 1;
    float a0 = 0.f, a1 = 0.f;
    int i = s;
    for (; i + 4 <= e; i += 4) {
        int2 p0 = ep[i], p1 = ep[i + 1], p2 = ep[i + 2], p3 = ep[i + 3];
        float v0 = __int_as_float(p0.y), v1 = __int_as_float(p1.y);
        float v2 = __int_as_float(p2.y), v3 = __int_as_float(p3.y);
        unsigned int g0 = *(const unsigned int*)&sup[((size_t)p0.x << 7) + cb];
        unsigned int g1 = *(const unsigned int*)&sup[((size_t)p1.x << 7) + cb];
        unsigned int g2 = *(const unsigned int*)&sup[((size_t)p2.x << 7) + cb];
        unsigned int g3 = *(const unsigned int*)&sup[((size_t)p3.x << 7) + cb];
        a0 += v0 * b2f_lo(g0); a1 += v0 * b2f_hi(g0);
        a0 += v1 * b2f_lo(g1); a1 += v1 * b2f_hi(g1);
        a0 += v2 * b2f_lo(g2); a1 += v2 * b2f_hi(g2);
        a0 += v3 * b2f_lo(g3); a1 += v3 * b2f_hi(g3);
    }
    for (; i < e; ++i) {
        int2 p0 = ep[i];
        float v0 = __int_as_float(p0.y);
        unsigned int g0 = *(const unsigned int*)&sup[((size_t)p0.x << 7) + cb];
        a0 += v0 * b2f_lo(g0); a1 += v0 * b2f_hi(g0);
    }
    float2 bv = *(const float2*)&bias[cb];
    a0 += bv.x; a1 += bv.y;
    a0 = (a0 >= 0.f) ? a0 : SLOPE * a0;
    a1 = (a1 >= 0.f) ? a1 : SLOPE * a1;
    *(float2*)&out[((size_t)row << 7) + cb] = make_float2(a0, a1);
}

// ---------------- launch ----------------
extern "C" void kernel_launch(void* const* d_in, const int* in_sizes, int n_in,
                              void* d_out, int out_size, void* d_ws, size_t ws_size,
                              hipStream_t stream) {
    const float* x     = (const float*)d_in[0];
    const int*   arows = (const int*)d_in[1];
    const int*   acols = (const int*)d_in[2];
    const float* avals = (const float*)d_in[3];
    const float* W1 = (const float*)d_in[4];
    const float* b1 = (const float*)d_in[5];
    const float* W2 = (const float*)d_in[6];
    const float* b2 = (const float*)d_in[7];
    const float* W3 = (const float*)d_in[8];
    const float* b3 = (const float*)d_in[9];
    float* out = (float*)d_out;

    char* ws = (char*)d_ws;
    unsigned short* xb   = (unsigned short*)(ws);                 // 100000*512 bf16
    unsigned short* bufS = (unsigned short*)(ws + 102400000);     // 100000*256 bf16
    unsigned short* bufH = (unsigned short*)(ws + 153600000);     // 100000*256 bf16
    int2*  epack = (int2*)(ws + 204800000);                       // NNZ int2 = 25,600,000 B
    int*   roff = (int*)  (ws + 230400000);                       // N+1 i32
    int*   curs = (int*)  (ws + 230800128);                       // N i32 (dead after scatter)
    int*   cnts = (int*)  (ws + 231200128);                       // N i32 (dead after scan_apply)
    // overlays:
    unsigned short* Wt1 = (unsigned short*)(ws + 231200128);      // over cnts
    unsigned short* Wt2 = (unsigned short*)(ws + 230800128);      // over curs
    unsigned short* Wt3 = (unsigned short*)(ws + 230800128 + 131072);
    int* bsum = (int*)(ws + 153600000);          // over bufH (first written by spmm L1)
    int* boff = (int*)(ws + 153600000 + 512);

    // CSR build
    hipMemsetAsync(cnts, 0, N_NODES * sizeof(int), stream);
    hist_kernel<<<NNZ_E / 256, 256, 0, stream>>>(arows, cnts);
    chunk_sum_kernel<<<NBLK_SCAN, 256, 0, stream>>>(cnts, bsum);
    bsum_scan_kernel<<<1, 128, 0, stream>>>(bsum, boff);
    scan_apply_kernel<<<NBLK_SCAN, 256, 0, stream>>>(cnts, boff, roff, curs);
    wprep_kernel<<<(512 * 256 + 255) / 256, 256, 0, stream>>>(W1, Wt1, 512, 256); // cnts dead
    scatter_kernel<<<NNZ_E / 256, 256, 0, stream>>>(arows, acols, avals, curs, epack);
    wprep_kernel<<<(256 * 256 + 255) / 256, 256, 0, stream>>>(W2, Wt2, 256, 256); // curs dead
    wprep_kernel<<<(256 * 128 + 255) / 256, 256, 0, stream>>>(W3, Wt3, 256, 128);

    conv_kernel<<<(100000 * 512 / 4 + 255) / 256, 256, 0, stream>>>(x, xb, 100000 * 512 / 4);

    const int gyc = (N_NODES + 127) / 128;  // 782

    // layer 1
    gemm_bf16_128<<<dim3(2, gyc), 256, 0, stream>>>(xb, Wt1, bufS, N_NODES, 512, 256);
    spmm256b_kernel<<<25000, 256, 0, stream>>>(roff, epack, bufS, b1, bufH);
    // layer 2
    gemm_bf16_128<<<dim3(2, gyc), 256, 0, stream>>>(bufH, Wt2, bufS, N_NODES, 256, 256);
    spmm256b_kernel<<<25000, 256, 0, stream>>>(roff, epack, bufS, b2, bufH);
    // layer 3
    gemm_bf16_128<<<dim3(1, gyc), 256, 0, stream>>>(bufH, Wt3, bufS, N_NODES, 256, 128);
    spmm128f_kernel<<<25000, 256, 0, stream>>>(roff, epack, bufS, b3, out);
}